// Round 1
// baseline (144.297 us; speedup 1.0000x reference)
//
#include <hip/hip_runtime.h>
#include <math.h>

#define B_ 2
#define U_ 32
#define V_ 2048
#define IN_ 256
#define ST_ 512
#define H_ 8
#define BU_ 64
#define NR_ 512

// ws layout (float offsets)
#define WS_SLN   0u          // [B][V][IN]      1048576
#define WS_SLNT  1048576u    // [B][IN][V]      1048576
#define WS_SCALE 2097152u    // [BU][2560]      163840  (q:0 k:512 v:768 e:1024 f1:1536 f2:2048)
#define WS_T     2260992u    // [NR][IN]        131072
#define WS_CB    2392064u    // [NR]            512
#define WS_P     2392576u    // [NR][V]         1048576
#define WS_PMAX  3441152u    // [NR][8]         4096
#define WS_SSUM  3445248u    // [NR]            512
#define WS_CTXP  3445760u    // [8][NR][IN]     1048576
#define WS_M2    4494336u    // [BU][512]       32768
#define WS_AO    4527104u    // [BU][512]       32768
#define WS_H2    4559872u    // [BU][512]       32768
// total 4592640 floats = ~17.5 MB

__device__ __forceinline__ float wsum(float v){
  #pragma unroll
  for(int m=32;m>0;m>>=1) v += __shfl_xor(v, m, 64);
  return v;
}
__device__ __forceinline__ float wmax(float v){
  #pragma unroll
  for(int m=32;m>0;m>>=1) v = fmaxf(v, __shfl_xor(v, m, 64));
  return v;
}

// ---------------- K1: sender layernorm + transpose (128 blocks x 256) ----------------
__global__ __launch_bounds__(256) void k_sln(const float* __restrict__ snd,
    const float* __restrict__ g, const float* __restrict__ bb, float* __restrict__ ws){
  __shared__ float tile[32][261];
  const int tid = threadIdx.x, wave = tid>>6, lane = tid&63;
  const int rowbase = blockIdx.x * 32;            // sender row base (B*V=4096 rows)
  const int b = rowbase >> 11, vloc = rowbase & 2047;
  float4 gg  = *(const float4*)(g  + lane*4);
  float4 bbv = *(const float4*)(bb + lane*4);
  for(int it=0; it<8; ++it){
    int rl = it*4 + wave;
    int r  = rowbase + rl;
    float4 x = *(const float4*)(snd + (size_t)r*IN_ + lane*4);
    float s = x.x+x.y+x.z+x.w;
    float q = x.x*x.x+x.y*x.y+x.z*x.z+x.w*x.w;
    s = wsum(s); q = wsum(q);
    float mu = s*(1.0f/256.0f);
    float rv = rsqrtf(q*(1.0f/256.0f) - mu*mu + 1e-5f);
    float4 y;
    y.x = (x.x-mu)*rv*gg.x + bbv.x;
    y.y = (x.y-mu)*rv*gg.y + bbv.y;
    y.z = (x.z-mu)*rv*gg.z + bbv.z;
    y.w = (x.w-mu)*rv*gg.w + bbv.w;
    *(float4*)(ws + WS_SLN + (size_t)r*IN_ + lane*4) = y;
    tile[rl][lane*4+0] = y.x;
    tile[rl][lane*4+1] = y.y;
    tile[rl][lane*4+2] = y.z;
    tile[rl][lane*4+3] = y.w;
  }
  __syncthreads();
  const int vh = lane & 31, ih = lane >> 5;
  for(int it=0; it<128; ++it){
    int i = it*2 + ih;
    ws[WS_SLNT + ((size_t)b*IN_ + i)*V_ + vloc + vh] = tile[vh][i];
  }
}

// ---------------- K2: all six modulation scale vectors (80 blocks x 256) ----------------
__global__ __launch_bounds__(256) void k_scales(const float* __restrict__ codes,
    const float* __restrict__ Cq, const float* __restrict__ Ck, const float* __restrict__ Cv,
    const float* __restrict__ Ce, const float* __restrict__ C1, const float* __restrict__ C2,
    float* __restrict__ ws){
  const int cc = blockIdx.x % 10, bg = blockIdx.x / 10;   // colchunk, bu-group(8)
  const int col = cc*256 + threadIdx.x;                   // 0..2559 virtual col
  const float* Cp; int loc;
  if(col < 512){ Cp = Cq; loc = col; }
  else if(col < 768){ Cp = Ck; loc = col - 512; }
  else if(col < 1024){ Cp = Cv; loc = col - 768; }
  else if(col < 1536){ Cp = Ce; loc = col - 1024; }
  else if(col < 2048){ Cp = C1; loc = col - 1536; }
  else { Cp = C2; loc = col - 2048; }
  const float4* wrow = (const float4*)(Cp + (size_t)loc*256);
  const float* cod = codes + (size_t)bg*8*256;
  float acc[8] = {0,0,0,0,0,0,0,0};
  for(int c4=0; c4<64; ++c4){
    float4 w = wrow[c4];
    #pragma unroll
    for(int k=0;k<8;++k){
      float4 c = *(const float4*)(cod + k*256 + c4*4);   // wave-uniform
      acc[k] += w.x*c.x + w.y*c.y + w.z*c.z + w.w*c.w;
    }
  }
  #pragma unroll
  for(int k=0;k<8;++k)
    ws[WS_SCALE + (size_t)(bg*8+k)*2560 + col] = 1.0f + acc[k];
}

// ---------------- K3: receiver LN + q head-slice + t_k + cb (512 blocks = bu x h) ----------------
__global__ __launch_bounds__(256) void k_qt(const float* __restrict__ rst,
    const float* __restrict__ lg, const float* __restrict__ lb,
    const float* __restrict__ Wq, const float* __restrict__ bq,
    const float* __restrict__ Wk, const float* __restrict__ bk,
    float* __restrict__ ws){
  const int bu = blockIdx.x >> 3, h = blockIdx.x & 7;
  const int b = bu >> 5, u = bu & 31;
  const int r = (b*8 + h)*32 + u;
  const int tid = threadIdx.x, wave = tid>>6, lane = tid&63;
  __shared__ float xm[512];
  __shared__ float qv[64];
  __shared__ float red[4][65];
  __shared__ float rsm[4], rqm[4];
  // receiver layernorm (redundant per h; cheap)
  float2 x2 = *(const float2*)(rst + (size_t)bu*512 + tid*2);
  float s = x2.x + x2.y, q = x2.x*x2.x + x2.y*x2.y;
  s = wsum(s); q = wsum(q);
  if(lane==0){ rsm[wave] = s; rqm[wave] = q; }
  __syncthreads();
  float S = rsm[0]+rsm[1]+rsm[2]+rsm[3];
  float Q = rqm[0]+rqm[1]+rqm[2]+rqm[3];
  float mu = S*(1.0f/512.0f);
  float rv = rsqrtf(Q*(1.0f/512.0f) - mu*mu + 1e-5f);
  const float* scal = ws + WS_SCALE + (size_t)bu*2560;
  xm[tid*2]   = ((x2.x-mu)*rv*lg[tid*2]   + lb[tid*2])   * scal[tid*2];
  xm[tid*2+1] = ((x2.y-mu)*rv*lg[tid*2+1] + lb[tid*2+1]) * scal[tid*2+1];
  __syncthreads();
  // q slice for this head: 64 outputs, 4-way K split
  {
    const int o = tid & 63, sp = tid >> 6;
    const float4* wq = (const float4*)(Wq + (size_t)(h*64 + o)*512 + sp*128);
    const float* xp = xm + sp*128;
    float acc = 0.f;
    #pragma unroll 8
    for(int c4=0;c4<32;++c4){
      float4 w = wq[c4];
      acc += w.x*xp[c4*4] + w.y*xp[c4*4+1] + w.z*xp[c4*4+2] + w.w*xp[c4*4+3];
    }
    red[sp][o] = acc;
  }
  __syncthreads();
  if(tid < 64)
    qv[tid] = red[0][tid]+red[1][tid]+red[2][tid]+red[3][tid] + bq[h*64+tid];
  __syncthreads();
  if(tid < 64){
    float p = qv[tid] * bk[h*64+tid];
    p = wsum(p);
    if(tid==0) ws[WS_CB + r] = p;
  }
  // t[r][i] = scale_k[i] * sum_d qv[d]*Wk[h*64+d][i]
  {
    float acc = 0.f;
    #pragma unroll 4
    for(int d=0; d<64; ++d)
      acc += qv[d] * Wk[(size_t)(h*64+d)*256 + tid];
    ws[WS_T + (size_t)r*256 + tid] = acc * scal[512 + tid];
  }
}

// ---------------- K4: scores GEMM + partial row-max (512 blocks) ----------------
__global__ __launch_bounds__(256) void k_scores(float* __restrict__ ws){
  const int rg = blockIdx.x >> 3, vc = blockIdx.x & 7;  // rowgroup(8 rows), v-chunk(256)
  const int tid = threadIdx.x, lane = tid & 63;
  const int wg = __builtin_amdgcn_readfirstlane(tid >> 6);
  const int r0 = rg*8 + wg*2;
  const int b = rg >> 5;
  const int v0 = vc*256 + lane*4;
  const float* sT = ws + WS_SLNT + (size_t)b*256*2048;
  const float* T0 = ws + WS_T + (size_t)r0*256;
  const float* T1 = T0 + 256;
  float4 a0 = {0,0,0,0}, a1 = {0,0,0,0};
  #pragma unroll 4
  for(int i=0;i<256;++i){
    float4 sv = *(const float4*)(sT + (size_t)i*2048 + v0);
    float t0 = T0[i], t1 = T1[i];
    a0.x += t0*sv.x; a0.y += t0*sv.y; a0.z += t0*sv.z; a0.w += t0*sv.w;
    a1.x += t1*sv.x; a1.y += t1*sv.y; a1.z += t1*sv.z; a1.w += t1*sv.w;
  }
  const float cb0 = ws[WS_CB + r0], cb1 = ws[WS_CB + r0 + 1];
  a0.x = (a0.x+cb0)*0.125f; a0.y = (a0.y+cb0)*0.125f; a0.z = (a0.z+cb0)*0.125f; a0.w = (a0.w+cb0)*0.125f;
  a1.x = (a1.x+cb1)*0.125f; a1.y = (a1.y+cb1)*0.125f; a1.z = (a1.z+cb1)*0.125f; a1.w = (a1.w+cb1)*0.125f;
  *(float4*)(ws + WS_P + (size_t)r0*2048 + v0) = a0;
  *(float4*)(ws + WS_P + (size_t)(r0+1)*2048 + v0) = a1;
  float m0 = fmaxf(fmaxf(a0.x,a0.y),fmaxf(a0.z,a0.w)); m0 = wmax(m0);
  float m1 = fmaxf(fmaxf(a1.x,a1.y),fmaxf(a1.z,a1.w)); m1 = wmax(m1);
  if(lane==0){
    ws[WS_PMAX + (size_t)r0*8 + vc] = m0;
    ws[WS_PMAX + (size_t)(r0+1)*8 + vc] = m1;
  }
}

// ---------------- K5: row softmax exp + sum (512 blocks = rows) ----------------
__global__ __launch_bounds__(256) void k_softmax(float* __restrict__ ws){
  const int r = blockIdx.x, tid = threadIdx.x, wave = tid>>6, lane = tid&63;
  const float* pm = ws + WS_PMAX + (size_t)r*8;
  float M = pm[0];
  #pragma unroll
  for(int k=1;k<8;++k) M = fmaxf(M, pm[k]);
  float* P = ws + WS_P + (size_t)r*2048;
  float ssum = 0.f;
  #pragma unroll
  for(int k=0;k<8;++k){
    int idx = k*256 + tid;
    float e = __expf(P[idx] - M);
    P[idx] = e;
    ssum += e;
  }
  ssum = wsum(ssum);
  __shared__ float rs[4];
  if(lane==0) rs[wave] = ssum;
  __syncthreads();
  if(tid==0) ws[WS_SSUM + r] = rs[0]+rs[1]+rs[2]+rs[3];
}

// ---------------- K6: ctx partial GEMM (512 blocks) ----------------
__global__ __launch_bounds__(256) void k_ctx(float* __restrict__ ws){
  const int rg = blockIdx.x >> 3, vc = blockIdx.x & 7;
  const int tid = threadIdx.x, lane = tid & 63;
  const int wg = __builtin_amdgcn_readfirstlane(tid >> 6);
  const int r0 = rg*8 + wg*2;
  const int b = rg >> 5;
  const int i0 = lane*4;
  const float* SL = ws + WS_SLN + ((size_t)b*2048 + vc*256)*256;
  const float* P0 = ws + WS_P + (size_t)r0*2048 + vc*256;
  const float* P1 = P0 + 2048;
  float4 a0={0,0,0,0}, a1={0,0,0,0};
  #pragma unroll 4
  for(int v=0; v<256; ++v){
    float4 sv = *(const float4*)(SL + (size_t)v*256 + i0);
    float p0 = P0[v], p1 = P1[v];
    a0.x += p0*sv.x; a0.y += p0*sv.y; a0.z += p0*sv.z; a0.w += p0*sv.w;
    a1.x += p1*sv.x; a1.y += p1*sv.y; a1.z += p1*sv.z; a1.w += p1*sv.w;
  }
  *(float4*)(ws + WS_CTXP + ((size_t)vc*512 + r0)*256 + i0) = a0;
  *(float4*)(ws + WS_CTXP + ((size_t)vc*512 + r0+1)*256 + i0) = a1;
}

// ---------------- K7: ctx reduce + scale_v + msg + scale_e (512 blocks = rows) ----------------
__global__ __launch_bounds__(256) void k_msg(const float* __restrict__ Wv, const float* __restrict__ bv,
    float* __restrict__ ws){
  const int r = blockIdx.x;
  const int b = r >> 8, h = (r >> 5) & 7, u = r & 31;
  const int bu = b*32 + u;
  const int tid = threadIdx.x;
  __shared__ float x[256];
  __shared__ float ps[4][64];
  const float invS = 1.0f / ws[WS_SSUM + r];
  {
    float s = 0.f;
    #pragma unroll
    for(int vc=0; vc<8; ++vc) s += ws[WS_CTXP + ((size_t)vc*512 + r)*256 + tid];
    x[tid] = s * ws[WS_SCALE + (size_t)bu*2560 + 768 + tid] * invS;
  }
  __syncthreads();
  {
    const int o = tid & 63, sp = tid >> 6;
    const float4* wv = (const float4*)(Wv + (size_t)(h*64+o)*256 + sp*64);
    const float* xp = x + sp*64;
    float acc = 0.f;
    #pragma unroll
    for(int c4=0;c4<16;++c4){
      float4 w = wv[c4];
      acc += w.x*xp[c4*4]+w.y*xp[c4*4+1]+w.z*xp[c4*4+2]+w.w*xp[c4*4+3];
    }
    ps[sp][o] = acc;
  }
  __syncthreads();
  if(tid < 64){
    float m = ps[0][tid]+ps[1][tid]+ps[2][tid]+ps[3][tid] + bv[h*64+tid];
    m *= ws[WS_SCALE + (size_t)bu*2560 + 1024 + h*64 + tid];
    ws[WS_M2 + (size_t)bu*512 + h*64 + tid] = m;
  }
}

// ---------------- K8: exit projection (256 blocks) ----------------
__global__ __launch_bounds__(256) void k_exit(const float* __restrict__ We, const float* __restrict__ be,
    const float* __restrict__ lsa, float* __restrict__ ws){
  const int bu = blockIdx.x >> 2, st = blockIdx.x & 3;
  const int tid = threadIdx.x;
  const int s = st*128 + (tid & 127), sp = tid >> 7;
  __shared__ float ps[2][128];
  const float4* we = (const float4*)(We + (size_t)s*512 + sp*256);
  const float* m2 = ws + WS_M2 + (size_t)bu*512 + sp*256;
  float acc = 0.f;
  #pragma unroll 8
  for(int c4=0;c4<64;++c4){
    float4 w = we[c4];
    acc += w.x*m2[c4*4]+w.y*m2[c4*4+1]+w.z*m2[c4*4+2]+w.w*m2[c4*4+3];
  }
  ps[sp][tid&127] = acc;
  __syncthreads();
  if(sp==0)
    ws[WS_AO + (size_t)bu*512 + s] = (ps[0][tid] + ps[1][tid] + be[s]) * lsa[s];
}

// ---------------- K9: FFN layernorm + W1 + gelu + scale2 (256 blocks) ----------------
__global__ __launch_bounds__(256) void k_ffn1(const float* __restrict__ lg, const float* __restrict__ lb,
    const float* __restrict__ W1, const float* __restrict__ b1, float* __restrict__ ws){
  const int bu = blockIdx.x >> 2, ot = blockIdx.x & 3;
  const int tid = threadIdx.x, wave = tid>>6, lane = tid&63;
  __shared__ float xr[512];
  __shared__ float rsm[4], rqm[4];
  __shared__ float ps[2][128];
  float2 x2 = *(const float2*)(ws + WS_AO + (size_t)bu*512 + tid*2);
  float s = x2.x+x2.y, q = x2.x*x2.x+x2.y*x2.y;
  s = wsum(s); q = wsum(q);
  if(lane==0){ rsm[wave]=s; rqm[wave]=q; }
  __syncthreads();
  float S=rsm[0]+rsm[1]+rsm[2]+rsm[3], Q=rqm[0]+rqm[1]+rqm[2]+rqm[3];
  float mu = S*(1.0f/512.0f);
  float rv = rsqrtf(Q*(1.0f/512.0f) - mu*mu + 1e-5f);
  const float* scal = ws + WS_SCALE + (size_t)bu*2560;
  xr[tid*2]   = ((x2.x-mu)*rv*lg[tid*2]   + lb[tid*2])   * scal[1536 + tid*2];
  xr[tid*2+1] = ((x2.y-mu)*rv*lg[tid*2+1] + lb[tid*2+1]) * scal[1536 + tid*2+1];
  __syncthreads();
  const int o = ot*128 + (tid & 127), sp = tid >> 7;
  const float4* w1 = (const float4*)(W1 + (size_t)o*512 + sp*256);
  const float* xp = xr + sp*256;
  float acc = 0.f;
  #pragma unroll 8
  for(int c4=0;c4<64;++c4){
    float4 w = w1[c4];
    acc += w.x*xp[c4*4]+w.y*xp[c4*4+1]+w.z*xp[c4*4+2]+w.w*xp[c4*4+3];
  }
  ps[sp][tid&127] = acc;
  __syncthreads();
  if(sp==0){
    float hh = ps[0][tid] + ps[1][tid] + b1[o];
    float ge = 0.5f*hh*(1.0f + erff(hh*0.70710678118654752f));
    ws[WS_H2 + (size_t)bu*512 + o] = ge * scal[2048 + o];
  }
}

// ---------------- K10: FFN W2 + residual -> out (256 blocks) ----------------
__global__ __launch_bounds__(256) void k_ffn2(const float* __restrict__ W2, const float* __restrict__ b2,
    const float* __restrict__ lsf, const float* __restrict__ ws, float* __restrict__ out){
  const int bu = blockIdx.x >> 2, st = blockIdx.x & 3;
  const int tid = threadIdx.x;
  const int s = st*128 + (tid & 127), sp = tid >> 7;
  __shared__ float ps[2][128];
  const float4* w2 = (const float4*)(W2 + (size_t)s*512 + sp*256);
  const float* hp = ws + WS_H2 + (size_t)bu*512 + sp*256;
  float acc = 0.f;
  #pragma unroll 8
  for(int c4=0;c4<64;++c4){
    float4 w = w2[c4];
    acc += w.x*hp[c4*4]+w.y*hp[c4*4+1]+w.z*hp[c4*4+2]+w.w*hp[c4*4+3];
  }
  ps[sp][tid&127] = acc;
  __syncthreads();
  if(sp==0)
    out[(size_t)bu*512 + s] = ws[WS_AO + (size_t)bu*512 + s]
                            + (ps[0][tid]+ps[1][tid] + b2[s]) * lsf[s];
}

extern "C" void kernel_launch(void* const* d_in, const int* in_sizes, int n_in,
                              void* d_out, int out_size, void* d_ws, size_t ws_size,
                              hipStream_t stream) {
  (void)in_sizes; (void)n_in; (void)out_size; (void)ws_size;
  const float* rst   = (const float*)d_in[0];
  // d_in[1] receiver_signatures: unused by reference
  const float* codes = (const float*)d_in[2];
  const float* snd   = (const float*)d_in[3];
  const float* ln_s_g = (const float*)d_in[4];
  const float* ln_s_b = (const float*)d_in[5];
  const float* ln_r_g = (const float*)d_in[6];
  const float* ln_r_b = (const float*)d_in[7];
  const float* Wq = (const float*)d_in[8];
  const float* bq = (const float*)d_in[9];
  const float* Cq = (const float*)d_in[10];
  const float* Wk = (const float*)d_in[11];
  const float* bk = (const float*)d_in[12];
  const float* Ck = (const float*)d_in[13];
  const float* Wv = (const float*)d_in[14];
  const float* bv = (const float*)d_in[15];
  const float* Cv = (const float*)d_in[16];
  const float* We = (const float*)d_in[17];
  const float* be = (const float*)d_in[18];
  const float* Ce = (const float*)d_in[19];
  const float* lsa = (const float*)d_in[20];
  const float* ln_f_g = (const float*)d_in[21];
  const float* ln_f_b = (const float*)d_in[22];
  const float* W1 = (const float*)d_in[23];
  const float* b1 = (const float*)d_in[24];
  const float* C1 = (const float*)d_in[25];
  const float* W2 = (const float*)d_in[26];
  const float* b2 = (const float*)d_in[27];
  const float* C2 = (const float*)d_in[28];
  const float* lsf = (const float*)d_in[29];
  float* ws  = (float*)d_ws;
  float* out = (float*)d_out;

  k_sln    <<<128, 256, 0, stream>>>(snd, ln_s_g, ln_s_b, ws);
  k_scales <<<80,  256, 0, stream>>>(codes, Cq, Ck, Cv, Ce, C1, C2, ws);
  k_qt     <<<512, 256, 0, stream>>>(rst, ln_r_g, ln_r_b, Wq, bq, Wk, bk, ws);
  k_scores <<<512, 256, 0, stream>>>(ws);
  k_softmax<<<512, 256, 0, stream>>>(ws);
  k_ctx    <<<512, 256, 0, stream>>>(ws);
  k_msg    <<<512, 256, 0, stream>>>(Wv, bv, ws);
  k_exit   <<<256, 256, 0, stream>>>(We, be, lsa, ws);
  k_ffn1   <<<256, 256, 0, stream>>>(ln_f_g, ln_f_b, W1, b1, ws);
  k_ffn2   <<<256, 256, 0, stream>>>(W2, b2, lsf, ws, out);
}

// Round 2
// 124.261 us; speedup vs baseline: 1.1612x; 1.1612x over previous
//
#include <hip/hip_runtime.h>
#include <math.h>

#define B_ 2
#define U_ 32
#define V_ 2048
#define IN_ 256
#define ST_ 512
#define H_ 8
#define BU_ 64
#define NR_ 512

// ws layout (float offsets)
#define WS_SLN   0u          // [B][V][IN]      1048576
#define WS_SLNT  1048576u    // [B][IN][V]      1048576
#define WS_SCALE 2097152u    // [BU][2560]      163840  (q:0 k:512 v:768 e:1024 f1:1536 f2:2048)
#define WS_T     2260992u    // [NR][IN]        131072
#define WS_CB    2392064u    // [NR]            512
#define WS_SSUMP 2392576u    // [NR][8]         4096
#define WS_CTXP  2396672u    // [8][NR][IN]     1048576
#define WS_M2    3445248u    // [BU][512]       32768
#define WS_AO    3478016u    // [BU][512]       32768
#define WS_H2    3510784u    // [BU][512]       32768
// total 3543552 floats ~= 13.5 MB

__device__ __forceinline__ float wsum(float v){
  #pragma unroll
  for(int m=32;m>0;m>>=1) v += __shfl_xor(v, m, 64);
  return v;
}

// ---------------- K1: fused sender-LN+transpose (blocks 0..127) and scales GEMM (blocks 128..447) ----------------
__global__ __launch_bounds__(256) void k_pre(const float* __restrict__ snd,
    const float* __restrict__ g, const float* __restrict__ bb,
    const float* __restrict__ codes,
    const float* __restrict__ Cq, const float* __restrict__ Ck, const float* __restrict__ Cv,
    const float* __restrict__ Ce, const float* __restrict__ C1, const float* __restrict__ C2,
    float* __restrict__ ws){
  __shared__ float tile[32][261];
  __shared__ float cds[8][256];
  const int tid = threadIdx.x;
  if(blockIdx.x < 128){
    // ---- sender layernorm + transpose ----
    const int wave = tid>>6, lane = tid&63;
    const int rowbase = blockIdx.x * 32;
    const int b = rowbase >> 11, vloc = rowbase & 2047;
    float4 gg  = *(const float4*)(g  + lane*4);
    float4 bbv = *(const float4*)(bb + lane*4);
    for(int it=0; it<8; ++it){
      int rl = it*4 + wave;
      int r  = rowbase + rl;
      float4 x = *(const float4*)(snd + (size_t)r*IN_ + lane*4);
      float s = x.x+x.y+x.z+x.w;
      float q = x.x*x.x+x.y*x.y+x.z*x.z+x.w*x.w;
      s = wsum(s); q = wsum(q);
      float mu = s*(1.0f/256.0f);
      float rv = rsqrtf(q*(1.0f/256.0f) - mu*mu + 1e-5f);
      float4 y;
      y.x = (x.x-mu)*rv*gg.x + bbv.x;
      y.y = (x.y-mu)*rv*gg.y + bbv.y;
      y.z = (x.z-mu)*rv*gg.z + bbv.z;
      y.w = (x.w-mu)*rv*gg.w + bbv.w;
      *(float4*)(ws + WS_SLN + (size_t)r*IN_ + lane*4) = y;
      tile[rl][lane*4+0] = y.x;
      tile[rl][lane*4+1] = y.y;
      tile[rl][lane*4+2] = y.z;
      tile[rl][lane*4+3] = y.w;
    }
    __syncthreads();
    const int vh = tid & 31;
    const int ibase = (tid >> 5);    // 8 groups
    for(int it=0; it<32; ++it){
      int i = it*8 + ibase;
      ws[WS_SLNT + ((size_t)b*IN_ + i)*V_ + vloc + vh] = tile[vh][i];
    }
  } else {
    // ---- modulation scales: scale[bu][col] = 1 + sum_c codes[bu][c]*C[col][c] ----
    const int idx = blockIdx.x - 128;
    const int cg = idx % 40, bg = idx / 40;         // 40 colgroups x 8 bugroups
    // stage codes tile (8 bu x 256) coalesced
    #pragma unroll
    for(int j=0;j<8;++j){
      int fi = j*256 + tid;
      cds[fi>>8][fi&255] = codes[(size_t)(bg*8)*256 + fi];
    }
    __syncthreads();
    const int q = tid & 3;            // c-quarter
    const int col = cg*64 + (tid >> 2);
    const float* Cp; int loc;
    if(col < 512){ Cp = Cq; loc = col; }
    else if(col < 768){ Cp = Ck; loc = col - 512; }
    else if(col < 1024){ Cp = Cv; loc = col - 768; }
    else if(col < 1536){ Cp = Ce; loc = col - 1024; }
    else if(col < 2048){ Cp = C1; loc = col - 1536; }
    else { Cp = C2; loc = col - 2048; }
    const float4* wrow = (const float4*)(Cp + (size_t)loc*256 + q*64);
    float acc[8] = {0,0,0,0,0,0,0,0};
    #pragma unroll 4
    for(int i=0;i<16;++i){
      float4 w = wrow[i];
      #pragma unroll
      for(int k=0;k<8;++k){
        const float4 c = *(const float4*)(&cds[k][q*64 + i*4]);
        acc[k] += w.x*c.x + w.y*c.y + w.z*c.z + w.w*c.w;
      }
    }
    #pragma unroll
    for(int k=0;k<8;++k){
      acc[k] += __shfl_xor(acc[k], 1, 64);
      acc[k] += __shfl_xor(acc[k], 2, 64);
    }
    // each of the 4 lanes in the group stores 2 bu rows
    ws[WS_SCALE + (size_t)(bg*8 + q)*2560 + col]     = 1.0f + acc[q];
    ws[WS_SCALE + (size_t)(bg*8 + q + 4)*2560 + col] = 1.0f + acc[q+4];
  }
}

// ---------------- K2: receiver LN + q head-slice + t_k + cb (512 blocks = bu x h) ----------------
__global__ __launch_bounds__(256) void k_qt(const float* __restrict__ rst,
    const float* __restrict__ lg, const float* __restrict__ lb,
    const float* __restrict__ Wq, const float* __restrict__ bq,
    const float* __restrict__ Wk, const float* __restrict__ bk,
    float* __restrict__ ws){
  const int bu = blockIdx.x >> 3, h = blockIdx.x & 7;
  const int b = bu >> 5, u = bu & 31;
  const int r = (b*8 + h)*32 + u;
  const int tid = threadIdx.x, wave = tid>>6, lane = tid&63;
  __shared__ float xm[512];
  __shared__ float qv[64];
  __shared__ float red[4][65];
  __shared__ float rsm[4], rqm[4];
  float2 x2 = *(const float2*)(rst + (size_t)bu*512 + tid*2);
  float s = x2.x + x2.y, q = x2.x*x2.x + x2.y*x2.y;
  s = wsum(s); q = wsum(q);
  if(lane==0){ rsm[wave] = s; rqm[wave] = q; }
  __syncthreads();
  float S = rsm[0]+rsm[1]+rsm[2]+rsm[3];
  float Q = rqm[0]+rqm[1]+rqm[2]+rqm[3];
  float mu = S*(1.0f/512.0f);
  float rv = rsqrtf(Q*(1.0f/512.0f) - mu*mu + 1e-5f);
  const float* scal = ws + WS_SCALE + (size_t)bu*2560;
  xm[tid*2]   = ((x2.x-mu)*rv*lg[tid*2]   + lb[tid*2])   * scal[tid*2];
  xm[tid*2+1] = ((x2.y-mu)*rv*lg[tid*2+1] + lb[tid*2+1]) * scal[tid*2+1];
  __syncthreads();
  {
    const int o = tid & 63, sp = tid >> 6;
    const float4* wq = (const float4*)(Wq + (size_t)(h*64 + o)*512 + sp*128);
    const float* xp = xm + sp*128;
    float acc = 0.f;
    #pragma unroll 8
    for(int c4=0;c4<32;++c4){
      float4 w = wq[c4];
      acc += w.x*xp[c4*4] + w.y*xp[c4*4+1] + w.z*xp[c4*4+2] + w.w*xp[c4*4+3];
    }
    red[sp][o] = acc;
  }
  __syncthreads();
  if(tid < 64)
    qv[tid] = red[0][tid]+red[1][tid]+red[2][tid]+red[3][tid] + bq[h*64+tid];
  __syncthreads();
  if(tid < 64){
    float p = qv[tid] * bk[h*64+tid];
    p = wsum(p);
    if(tid==0) ws[WS_CB + r] = p;
  }
  {
    float acc = 0.f;
    #pragma unroll 4
    for(int d=0; d<64; ++d)
      acc += qv[d] * Wk[(size_t)(h*64+d)*256 + tid];
    ws[WS_T + (size_t)r*256 + tid] = acc * scal[512 + tid];
  }
}

// ---------------- K3: fused scores GEMM -> exp (no max) -> ctx GEMM (256 blocks) ----------------
// block = (rowgroup of 16 rows) x (v-chunk of 256). Wave w owns rows rg*16+w*4 .. +3.
__global__ __launch_bounds__(256) void k_scctx(float* __restrict__ ws){
  const int rg = blockIdx.x >> 3, vc = blockIdx.x & 7;
  const int tid = threadIdx.x, lane = tid & 63;
  const int w = __builtin_amdgcn_readfirstlane(tid >> 6);
  const int r0 = rg*16;
  const int b = rg >> 4;
  __shared__ float Tl[16][256];   // T rows for this rowgroup
  __shared__ float P[16][256];    // exp(scores) for this (rowgroup, v-chunk)
  // stage T (coalesced): 4096 floats
  {
    const float4* src = (const float4*)(ws + WS_T + (size_t)r0*256);
    float4* dst = (float4*)(&Tl[0][0]);
    #pragma unroll
    for(int j=0;j<4;++j) dst[j*256 + tid] = src[j*256 + tid];
  }
  __syncthreads();
  // ---- phase 1: scores + exp ----
  const int v0 = vc*256 + lane*4;
  const float* sT = ws + WS_SLNT + (size_t)b*IN_*V_;
  float4 a0={0,0,0,0}, a1={0,0,0,0}, a2={0,0,0,0}, a3={0,0,0,0};
  const float* T0 = &Tl[w*4+0][0];
  const float* T1 = &Tl[w*4+1][0];
  const float* T2 = &Tl[w*4+2][0];
  const float* T3 = &Tl[w*4+3][0];
  #pragma unroll 4
  for(int i=0;i<256;++i){
    float4 sv = *(const float4*)(sT + (size_t)i*V_ + v0);
    float t0 = T0[i], t1 = T1[i], t2 = T2[i], t3 = T3[i];
    a0.x += t0*sv.x; a0.y += t0*sv.y; a0.z += t0*sv.z; a0.w += t0*sv.w;
    a1.x += t1*sv.x; a1.y += t1*sv.y; a1.z += t1*sv.z; a1.w += t1*sv.w;
    a2.x += t2*sv.x; a2.y += t2*sv.y; a2.z += t2*sv.z; a2.w += t2*sv.w;
    a3.x += t3*sv.x; a3.y += t3*sv.y; a3.z += t3*sv.z; a3.w += t3*sv.w;
  }
  const int rw = r0 + w*4;
  {
    const float cb0 = ws[WS_CB + rw+0], cb1 = ws[WS_CB + rw+1];
    const float cb2 = ws[WS_CB + rw+2], cb3 = ws[WS_CB + rw+3];
    float4 e;
    float ss;
    e.x = __expf((a0.x+cb0)*0.125f); e.y = __expf((a0.y+cb0)*0.125f);
    e.z = __expf((a0.z+cb0)*0.125f); e.w = __expf((a0.w+cb0)*0.125f);
    *(float4*)(&P[w*4+0][lane*4]) = e;
    ss = wsum(e.x+e.y+e.z+e.w);
    if(lane==0) ws[WS_SSUMP + (size_t)(rw+0)*8 + vc] = ss;
    e.x = __expf((a1.x+cb1)*0.125f); e.y = __expf((a1.y+cb1)*0.125f);
    e.z = __expf((a1.z+cb1)*0.125f); e.w = __expf((a1.w+cb1)*0.125f);
    *(float4*)(&P[w*4+1][lane*4]) = e;
    ss = wsum(e.x+e.y+e.z+e.w);
    if(lane==0) ws[WS_SSUMP + (size_t)(rw+1)*8 + vc] = ss;
    e.x = __expf((a2.x+cb2)*0.125f); e.y = __expf((a2.y+cb2)*0.125f);
    e.z = __expf((a2.z+cb2)*0.125f); e.w = __expf((a2.w+cb2)*0.125f);
    *(float4*)(&P[w*4+2][lane*4]) = e;
    ss = wsum(e.x+e.y+e.z+e.w);
    if(lane==0) ws[WS_SSUMP + (size_t)(rw+2)*8 + vc] = ss;
    e.x = __expf((a3.x+cb3)*0.125f); e.y = __expf((a3.y+cb3)*0.125f);
    e.z = __expf((a3.z+cb3)*0.125f); e.w = __expf((a3.w+cb3)*0.125f);
    *(float4*)(&P[w*4+3][lane*4]) = e;
    ss = wsum(e.x+e.y+e.z+e.w);
    if(lane==0) ws[WS_SSUMP + (size_t)(rw+3)*8 + vc] = ss;
  }
  // ---- phase 2: ctx partial GEMM (each wave consumes only its own P rows; no barrier needed) ----
  const int i0 = lane*4;
  const float* SL = ws + WS_SLN + ((size_t)b*V_ + vc*256)*IN_;
  float4 c0={0,0,0,0}, c1={0,0,0,0}, c2={0,0,0,0}, c3={0,0,0,0};
  const float* P0 = &P[w*4+0][0];
  const float* P1 = &P[w*4+1][0];
  const float* P2 = &P[w*4+2][0];
  const float* P3 = &P[w*4+3][0];
  #pragma unroll 4
  for(int v=0; v<256; ++v){
    float4 sv = *(const float4*)(SL + (size_t)v*IN_ + i0);
    float p0 = P0[v], p1 = P1[v], p2 = P2[v], p3 = P3[v];
    c0.x += p0*sv.x; c0.y += p0*sv.y; c0.z += p0*sv.z; c0.w += p0*sv.w;
    c1.x += p1*sv.x; c1.y += p1*sv.y; c1.z += p1*sv.z; c1.w += p1*sv.w;
    c2.x += p2*sv.x; c2.y += p2*sv.y; c2.z += p2*sv.z; c2.w += p2*sv.w;
    c3.x += p3*sv.x; c3.y += p3*sv.y; c3.z += p3*sv.z; c3.w += p3*sv.w;
  }
  *(float4*)(ws + WS_CTXP + ((size_t)vc*NR_ + rw+0)*IN_ + i0) = c0;
  *(float4*)(ws + WS_CTXP + ((size_t)vc*NR_ + rw+1)*IN_ + i0) = c1;
  *(float4*)(ws + WS_CTXP + ((size_t)vc*NR_ + rw+2)*IN_ + i0) = c2;
  *(float4*)(ws + WS_CTXP + ((size_t)vc*NR_ + rw+3)*IN_ + i0) = c3;
}

// ---------------- K4: ctx reduce + scale_v + Wv + scale_e (512 blocks = rows) ----------------
__global__ __launch_bounds__(256) void k_msg(const float* __restrict__ Wv, const float* __restrict__ bv,
    float* __restrict__ ws){
  const int r = blockIdx.x;
  const int b = r >> 8, h = (r >> 5) & 7, u = r & 31;
  const int bu = b*32 + u;
  const int tid = threadIdx.x;
  __shared__ float x[256];
  __shared__ float ps[4][64];
  float ssum = 0.f;
  #pragma unroll
  for(int k=0;k<8;++k) ssum += ws[WS_SSUMP + (size_t)r*8 + k];
  const float invS = 1.0f / ssum;
  {
    float s = 0.f;
    #pragma unroll
    for(int vc=0; vc<8; ++vc) s += ws[WS_CTXP + ((size_t)vc*NR_ + r)*IN_ + tid];
    x[tid] = s * ws[WS_SCALE + (size_t)bu*2560 + 768 + tid] * invS;
  }
  __syncthreads();
  {
    const int o = tid & 63, sp = tid >> 6;
    const float4* wv = (const float4*)(Wv + (size_t)(h*64+o)*256 + sp*64);
    const float* xp = x + sp*64;
    float acc = 0.f;
    #pragma unroll
    for(int c4=0;c4<16;++c4){
      float4 w = wv[c4];
      acc += w.x*xp[c4*4]+w.y*xp[c4*4+1]+w.z*xp[c4*4+2]+w.w*xp[c4*4+3];
    }
    ps[sp][o] = acc;
  }
  __syncthreads();
  if(tid < 64){
    float m = ps[0][tid]+ps[1][tid]+ps[2][tid]+ps[3][tid] + bv[h*64+tid];
    m *= ws[WS_SCALE + (size_t)bu*2560 + 1024 + h*64 + tid];
    ws[WS_M2 + (size_t)bu*512 + h*64 + tid] = m;
  }
}

// ---------------- K5: exit projection (256 blocks) ----------------
__global__ __launch_bounds__(256) void k_exit(const float* __restrict__ We, const float* __restrict__ be,
    const float* __restrict__ lsa, float* __restrict__ ws){
  const int bu = blockIdx.x >> 2, st = blockIdx.x & 3;
  const int tid = threadIdx.x;
  const int s = st*128 + (tid & 127), sp = tid >> 7;
  __shared__ float ps[2][128];
  const float4* we = (const float4*)(We + (size_t)s*512 + sp*256);
  const float* m2 = ws + WS_M2 + (size_t)bu*512 + sp*256;
  float acc = 0.f;
  #pragma unroll 8
  for(int c4=0;c4<64;++c4){
    float4 w = we[c4];
    acc += w.x*m2[c4*4]+w.y*m2[c4*4+1]+w.z*m2[c4*4+2]+w.w*m2[c4*4+3];
  }
  ps[sp][tid&127] = acc;
  __syncthreads();
  if(sp==0)
    ws[WS_AO + (size_t)bu*512 + s] = (ps[0][tid] + ps[1][tid] + be[s]) * lsa[s];
}

// ---------------- K6: FFN layernorm + W1 + gelu + scale2 (256 blocks) ----------------
__global__ __launch_bounds__(256) void k_ffn1(const float* __restrict__ lg, const float* __restrict__ lb,
    const float* __restrict__ W1, const float* __restrict__ b1, float* __restrict__ ws){
  const int bu = blockIdx.x >> 2, ot = blockIdx.x & 3;
  const int tid = threadIdx.x, wave = tid>>6, lane = tid&63;
  __shared__ float xr[512];
  __shared__ float rsm[4], rqm[4];
  __shared__ float ps[2][128];
  float2 x2 = *(const float2*)(ws + WS_AO + (size_t)bu*512 + tid*2);
  float s = x2.x+x2.y, q = x2.x*x2.x+x2.y*x2.y;
  s = wsum(s); q = wsum(q);
  if(lane==0){ rsm[wave]=s; rqm[wave]=q; }
  __syncthreads();
  float S=rsm[0]+rsm[1]+rsm[2]+rsm[3], Q=rqm[0]+rqm[1]+rqm[2]+rqm[3];
  float mu = S*(1.0f/512.0f);
  float rv = rsqrtf(Q*(1.0f/512.0f) - mu*mu + 1e-5f);
  const float* scal = ws + WS_SCALE + (size_t)bu*2560;
  xr[tid*2]   = ((x2.x-mu)*rv*lg[tid*2]   + lb[tid*2])   * scal[1536 + tid*2];
  xr[tid*2+1] = ((x2.y-mu)*rv*lg[tid*2+1] + lb[tid*2+1]) * scal[1536 + tid*2+1];
  __syncthreads();
  const int o = ot*128 + (tid & 127), sp = tid >> 7;
  const float4* w1 = (const float4*)(W1 + (size_t)o*512 + sp*256);
  const float* xp = xr + sp*256;
  float acc = 0.f;
  #pragma unroll 8
  for(int c4=0;c4<64;++c4){
    float4 w = w1[c4];
    acc += w.x*xp[c4*4]+w.y*xp[c4*4+1]+w.z*xp[c4*4+2]+w.w*xp[c4*4+3];
  }
  ps[sp][tid&127] = acc;
  __syncthreads();
  if(sp==0){
    float hh = ps[0][tid] + ps[1][tid] + b1[o];
    float ge = 0.5f*hh*(1.0f + erff(hh*0.70710678118654752f));
    ws[WS_H2 + (size_t)bu*512 + o] = ge * scal[2048 + o];
  }
}

// ---------------- K7: FFN W2 + residual -> out (256 blocks) ----------------
__global__ __launch_bounds__(256) void k_ffn2(const float* __restrict__ W2, const float* __restrict__ b2,
    const float* __restrict__ lsf, const float* __restrict__ ws, float* __restrict__ out){
  const int bu = blockIdx.x >> 2, st = blockIdx.x & 3;
  const int tid = threadIdx.x;
  const int s = st*128 + (tid & 127), sp = tid >> 7;
  __shared__ float ps[2][128];
  const float4* w2 = (const float4*)(W2 + (size_t)s*512 + sp*256);
  const float* hp = ws + WS_H2 + (size_t)bu*512 + sp*256;
  float acc = 0.f;
  #pragma unroll 8
  for(int c4=0;c4<64;++c4){
    float4 w = w2[c4];
    acc += w.x*hp[c4*4]+w.y*hp[c4*4+1]+w.z*hp[c4*4+2]+w.w*hp[c4*4+3];
  }
  ps[sp][tid&127] = acc;
  __syncthreads();
  if(sp==0)
    out[(size_t)bu*512 + s] = ws[WS_AO + (size_t)bu*512 + s]
                            + (ps[0][tid]+ps[1][tid] + b2[s]) * lsf[s];
}

extern "C" void kernel_launch(void* const* d_in, const int* in_sizes, int n_in,
                              void* d_out, int out_size, void* d_ws, size_t ws_size,
                              hipStream_t stream) {
  (void)in_sizes; (void)n_in; (void)out_size; (void)ws_size;
  const float* rst   = (const float*)d_in[0];
  const float* codes = (const float*)d_in[2];
  const float* snd   = (const float*)d_in[3];
  const float* ln_s_g = (const float*)d_in[4];
  const float* ln_s_b = (const float*)d_in[5];
  const float* ln_r_g = (const float*)d_in[6];
  const float* ln_r_b = (const float*)d_in[7];
  const float* Wq = (const float*)d_in[8];
  const float* bq = (const float*)d_in[9];
  const float* Cq = (const float*)d_in[10];
  const float* Wk = (const float*)d_in[11];
  const float* bk = (const float*)d_in[12];
  const float* Ck = (const float*)d_in[13];
  const float* Wv = (const float*)d_in[14];
  const float* bv = (const float*)d_in[15];
  const float* Cv = (const float*)d_in[16];
  const float* We = (const float*)d_in[17];
  const float* be = (const float*)d_in[18];
  const float* Ce = (const float*)d_in[19];
  const float* lsa = (const float*)d_in[20];
  const float* ln_f_g = (const float*)d_in[21];
  const float* ln_f_b = (const float*)d_in[22];
  const float* W1 = (const float*)d_in[23];
  const float* b1 = (const float*)d_in[24];
  const float* C1 = (const float*)d_in[25];
  const float* W2 = (const float*)d_in[26];
  const float* b2 = (const float*)d_in[27];
  const float* C2 = (const float*)d_in[28];
  const float* lsf = (const float*)d_in[29];
  float* ws  = (float*)d_ws;
  float* out = (float*)d_out;

  k_pre   <<<448, 256, 0, stream>>>(snd, ln_s_g, ln_s_b, codes, Cq, Ck, Cv, Ce, C1, C2, ws);
  k_qt    <<<512, 256, 0, stream>>>(rst, ln_r_g, ln_r_b, Wq, bq, Wk, bk, ws);
  k_scctx <<<256, 256, 0, stream>>>(ws);
  k_msg   <<<512, 256, 0, stream>>>(Wv, bv, ws);
  k_exit  <<<256, 256, 0, stream>>>(We, be, lsa, ws);
  k_ffn1  <<<256, 256, 0, stream>>>(ln_f_g, ln_f_b, W1, b1, ws);
  k_ffn2  <<<256, 256, 0, stream>>>(W2, b2, lsf, ws, out);
}